// Round 1
// baseline (142.295 us; speedup 1.0000x reference)
//
#include <hip/hip_runtime.h>

#define B_SZ 256
#define D_SZ 256
#define M_SZ 65536
#define C_SZ 1000
#define TEMP 0.05f
#define EPSF 1e-6f

// ---- ws layout (bytes) ----
#define OFF_FCT     0          // float[D_SZ*C_SZ]  = 1,024,000 B  (transposed, pre-scaled)
#define OFF_NUMS    1024000    // int[C_SZ]
#define OFF_OFFS    1028096    // int[C_SZ]
#define OFF_RUN     1032192    // int[C_SZ]
#define OFF_MEMB    1036288    // int[M_SZ] = 262,144 B
#define OFF_ACC     1300480    // float[2]

__global__ void k_hist(const int* __restrict__ labels, int* __restrict__ nums) {
    int m = blockIdx.x * blockDim.x + threadIdx.x;
    if (m < M_SZ) atomicAdd(&nums[labels[m]], 1);
}

__global__ void k_prefix(const int* __restrict__ nums, int* __restrict__ offs,
                         int* __restrict__ run) {
    __shared__ int s[1024];
    int t = threadIdx.x;
    int own = (t < C_SZ) ? nums[t] : 0;
    s[t] = own;
    __syncthreads();
    // Hillis-Steele inclusive scan over 1024
    for (int d = 1; d < 1024; d <<= 1) {
        int v = (t >= d) ? s[t - d] : 0;
        __syncthreads();
        s[t] += v;
        __syncthreads();
    }
    if (t < C_SZ) {
        int e = s[t] - own;  // exclusive
        offs[t] = e;
        run[t] = e;
    }
}

__global__ void k_scatter(const int* __restrict__ labels, int* __restrict__ run,
                          int* __restrict__ members) {
    int m = blockIdx.x * blockDim.x + threadIdx.x;
    if (m < M_SZ) {
        int c = labels[m];
        int pos = atomicAdd(&run[c], 1);
        members[pos] = m;
    }
}

// One block per class: sum member feature rows; write transposed + pre-scaled:
// fct[d*C + c] = (sum_m features[m][d]) / (TEMP * max(nums,1))
__global__ void k_classsum(const float* __restrict__ features,
                           const int* __restrict__ members,
                           const int* __restrict__ offs,
                           const int* __restrict__ nums,
                           float* __restrict__ fct) {
    int c = blockIdx.x;
    int t = threadIdx.x;  // dim
    int beg = offs[c], n = nums[c];
    float acc = 0.f;
    for (int i = 0; i < n; ++i) {
        int row = members[beg + i];                  // broadcast load
        acc += features[(size_t)row * D_SZ + t];     // coalesced 1KB row read
    }
    float scale = 1.0f / (TEMP * (float)(n > 0 ? n : 1));
    fct[(size_t)t * C_SZ + c] = acc * scale;
}

// Fused: normalize 4 feat rows, sim = x . Fct, masked softmax (reference
// numerics), loss1/loss2 partial accumulation.
__launch_bounds__(256)
__global__ void k_loss(const float* __restrict__ feat,
                       const float* __restrict__ fct,
                       const int* __restrict__ nums,
                       const float* __restrict__ soft,
                       const int* __restrict__ indexes,
                       const int* __restrict__ labels,
                       const int* __restrict__ bil,
                       float* __restrict__ acc) {
    __shared__ float xs[4][D_SZ];
    __shared__ float rs[4];
    __shared__ float denom[4];
    __shared__ int tgt[4];
    __shared__ int srow[4];

    int t = threadIdx.x;
    int wid = t >> 6, lane = t & 63;
    int b0 = blockIdx.x * 4;

    // normalize 4 rows
    for (int bb = 0; bb < 4; ++bb) {
        float v = feat[(size_t)(b0 + bb) * D_SZ + t];
        float s = v * v;
        #pragma unroll
        for (int o = 32; o; o >>= 1) s += __shfl_down(s, o);
        if (lane == 0) rs[wid] = s;
        __syncthreads();
        float nrm = sqrtf(rs[0] + rs[1] + rs[2] + rs[3]);
        nrm = fmaxf(nrm, 1e-12f);
        xs[bb][t] = v / nrm;
        __syncthreads();  // protect rs before next iteration's write
    }
    if (t < 4) {
        tgt[t] = labels[indexes[b0 + t]];
        srow[t] = bil[b0 + t];
    }
    __syncthreads();

    // sim for 4 classes (c = t + 256k) x 4 batch rows
    float simr[4][4];
    #pragma unroll
    for (int k = 0; k < 4; ++k) {
        int c = t + 256 * k;
        float a0 = 0, a1 = 0, a2 = 0, a3 = 0;
        if (c < C_SZ) {
            for (int i = 0; i < D_SZ; ++i) {
                float f = fct[(size_t)i * C_SZ + c];  // coalesced across lanes
                a0 += xs[0][i] * f;
                a1 += xs[1][i] * f;
                a2 += xs[2][i] * f;
                a3 += xs[3][i] * f;
            }
        }
        simr[k][0] = a0; simr[k][1] = a1; simr[k][2] = a2; simr[k][3] = a3;
    }

    // exps + per-row denominators (reference: exp(sim)*mask, no max-shift)
    float er[4][4];
    float part[4] = {0, 0, 0, 0};
    #pragma unroll
    for (int k = 0; k < 4; ++k) {
        int c = t + 256 * k;
        float mk = 0.f;
        if (c < C_SZ) mk = (nums[c] > 0) ? 1.f : 0.f;
        #pragma unroll
        for (int bb = 0; bb < 4; ++bb) {
            float e = (c < C_SZ) ? expf(simr[k][bb]) * mk : 0.f;
            er[k][bb] = e;
            part[bb] += e;
        }
    }
    #pragma unroll
    for (int bb = 0; bb < 4; ++bb) {
        float s = part[bb];
        #pragma unroll
        for (int o = 32; o; o >>= 1) s += __shfl_down(s, o);
        __syncthreads();
        if (lane == 0) rs[wid] = s;
        __syncthreads();
        if (t == 0) denom[bb] = rs[0] + rs[1] + rs[2] + rs[3];
    }
    __syncthreads();

    // loss partials
    float p1 = 0.f, p2 = 0.f;
    for (int bb = 0; bb < 4; ++bb) {
        const float* sp = soft + (size_t)srow[bb] * C_SZ;
        float dn = denom[bb] + EPSF;
        #pragma unroll
        for (int k = 0; k < 4; ++k) {
            int c = t + 256 * k;
            if (c < C_SZ) {
                float logp = logf(er[k][bb] / dn + EPSF);
                p2 -= sp[c] * logp;
                if (c == tgt[bb]) p1 -= logp;
            }
        }
    }
    // reduce p1, p2
    #pragma unroll
    for (int o = 32; o; o >>= 1) {
        p1 += __shfl_down(p1, o);
        p2 += __shfl_down(p2, o);
    }
    __syncthreads();
    __shared__ float r1[4], r2[4];
    if (lane == 0) { r1[wid] = p1; r2[wid] = p2; }
    __syncthreads();
    if (t == 0) {
        atomicAdd(&acc[0], r1[0] + r1[1] + r1[2] + r1[3]);
        atomicAdd(&acc[1], r2[0] + r2[1] + r2[2] + r2[3]);
    }
}

__global__ void k_final(const float* __restrict__ acc,
                        const int* __restrict__ cur_epoch,
                        float* __restrict__ out) {
    if (threadIdx.x == 0 && blockIdx.x == 0) {
        float l1 = acc[0] / (float)B_SZ;
        float l2 = acc[1] / (float)B_SZ;
        out[0] = (cur_epoch[0] == 0) ? l1 : (0.5f * l1 + 0.5f * l2);
    }
}

extern "C" void kernel_launch(void* const* d_in, const int* in_sizes, int n_in,
                              void* d_out, int out_size, void* d_ws, size_t ws_size,
                              hipStream_t stream) {
    const float* feat     = (const float*)d_in[0];
    const float* features = (const float*)d_in[1];
    const float* soft     = (const float*)d_in[2];
    const int* indexes    = (const int*)d_in[3];
    const int* labels     = (const int*)d_in[4];
    const int* bil        = (const int*)d_in[5];
    const int* cur_epoch  = (const int*)d_in[6];

    char* ws = (char*)d_ws;
    float* fct   = (float*)(ws + OFF_FCT);
    int* nums    = (int*)(ws + OFF_NUMS);
    int* offs    = (int*)(ws + OFF_OFFS);
    int* run     = (int*)(ws + OFF_RUN);
    int* members = (int*)(ws + OFF_MEMB);
    float* acc   = (float*)(ws + OFF_ACC);

    hipMemsetAsync(nums, 0, C_SZ * sizeof(int), stream);
    hipMemsetAsync(acc, 0, 2 * sizeof(float), stream);

    k_hist<<<M_SZ / 256, 256, 0, stream>>>(labels, nums);
    k_prefix<<<1, 1024, 0, stream>>>(nums, offs, run);
    k_scatter<<<M_SZ / 256, 256, 0, stream>>>(labels, run, members);
    k_classsum<<<C_SZ, 256, 0, stream>>>(features, members, offs, nums, fct);
    k_loss<<<B_SZ / 4, 256, 0, stream>>>(feat, fct, nums, soft, indexes, labels, bil, acc);
    k_final<<<1, 64, 0, stream>>>(acc, cur_epoch, (float*)d_out);
}